// Round 11
// baseline (185.173 us; speedup 1.0000x reference)
//
#include <hip/hip_runtime.h>
#include <hip/hip_bf16.h>

// Problem constants (from reference)
#define N_NODES 50000
#define D_FEAT  128
#define N_EDGES 600000
#define HIDDEN  256
#define K_DIM   256   // 2*D_FEAT

#define BUCKET   64      // edge slots per node; P(Poisson(12) > 64) ~ 1e-30
#define ZERO_ROW 50000   // pad id; 50000 == 0xC350 -> single hipMemsetD16 value
#define M_TILE   32
#define NTILES   1563    // ceil(50000/32)
#define NPAD     (NTILES * M_TILE)   // 50016 bucket rows (tail-safe)
#define H_STRIDE 264     // u16 units; 132 u32 units

typedef __attribute__((ext_vector_type(8))) short bf16x8;   // 8 bf16 = 4 VGPRs
typedef __attribute__((ext_vector_type(4))) float f32x4;    // MFMA acc

__device__ __forceinline__ unsigned short f32_to_bf16(float f) {
    unsigned int u = __float_as_uint(f);
    unsigned int r = (u + 0x7fffu + ((u >> 16) & 1u)) >> 16;  // RNE
    return (unsigned short)r;
}
__device__ __forceinline__ unsigned int pack_bf16x2(float lo, float hi) {
    return (unsigned int)f32_to_bf16(lo) | ((unsigned int)f32_to_bf16(hi) << 16);
}
__device__ __forceinline__ float bf_lo(unsigned int v) {
    return __uint_as_float(v << 16);
}
__device__ __forceinline__ float bf_hi(unsigned int v) {
    return __uint_as_float(v & 0xffff0000u);
}

// ---------------------------------------------------------------------------
// K1: bucket fill (receiver-grouped u16 sender ids; slots beyond the fill
//     stay at the memset pad ZERO_ROW) + nodes f32 -> packed bf16 (incl.
//     zeroed pad row) + W repack Wp[kt][n][quad][j], k = kt*32+quad*8+j.
// ---------------------------------------------------------------------------
__global__ __launch_bounds__(256) void build_conv_repack(
    const int* __restrict__ senders,
    const int* __restrict__ receivers,
    const float* __restrict__ nodes,
    const float* __restrict__ W,
    unsigned short* __restrict__ edges16,  // [NPAD*BUCKET] pre-filled ZERO_ROW
    unsigned int* __restrict__ cnt,        // [N] pre-zeroed
    unsigned int* __restrict__ nb,         // [(N+1)*64] packed bf16x2
    unsigned short* __restrict__ Wp) {     // [65536]
    const int gid = blockIdx.x * 256 + threadIdx.x;
    const int gsz = gridDim.x * 256;
    for (int e = gid; e < N_EDGES; e += gsz) {
        int r = receivers[e];
        unsigned int slot = atomicAdd(&cnt[r], 1u);
        if (slot < (unsigned int)BUCKET)
            edges16[(size_t)r * BUCKET + slot] = (unsigned short)senders[e];
    }
    for (int p = gid; p < N_NODES * 64; p += gsz) {
        const float2 v = *(const float2*)(nodes + (size_t)p * 2);
        nb[p] = pack_bf16x2(v.x, v.y);
    }
    if (gid < 64) nb[(size_t)ZERO_ROW * 64 + gid] = 0u;   // zero pad row
    for (int t = gid; t < 65536; t += gsz) {
        int kt = t >> 13;
        int n  = (t >> 5) & 255;
        int q  = (t >> 3) & 3;
        int j  = t & 7;
        int k  = kt * 32 + q * 8 + j;
        Wp[t] = f32_to_bf16(W[k * 256 + n]);
    }
}

// ---------------------------------------------------------------------------
// K2: fused bucket-gather mean + concat + MFMA GEMM + bias + relu.
// Tile = 32 nodes x 256 hidden, 256 threads (4 waves); wave owns 8 rows,
// processed as 4 row-PAIRS. Per pair: 16 ep-words + 32 row-gathers issued
// together, all UNCONDITIONAL (pad slots pre-filled with ZERO_ROW by
// hipMemsetD16 -> zero contribution, no selects). Rows with c>16 take a
// rare wave-uniform overflow loop (also select-free). f32 accumulate,
// bf16 pack into LDS h (stride 264 u16: 2-way banks, free per m136).
// Phase B: 2x4 tiles of mfma_f32_16x16x32_bf16 over K=256 (R3..R10-verified).
// ---------------------------------------------------------------------------
__global__ __launch_bounds__(256) void gather_mean_gemm(
    const unsigned int* __restrict__ nb,
    const unsigned int* __restrict__ cnt,
    const unsigned short* __restrict__ edges16,
    const unsigned short* __restrict__ Wp,
    const float* __restrict__ bias,
    float* __restrict__ out) {
    __shared__ __align__(16) unsigned int h32[M_TILE * (H_STRIDE / 2)];

    const int m0   = blockIdx.x * M_TILE;
    const int tid  = threadIdx.x;
    const int wave = tid >> 6;
    const int lane = tid & 63;

    // per-row clamped counts (wave-uniform values; tail rows -> 0)
    unsigned int cc[8];
    #pragma unroll
    for (int i = 0; i < 8; i++) {
        int m = m0 + wave * 8 + i;
        unsigned int c = (m < N_NODES) ? cnt[m] : 0u;
        cc[i] = c < (unsigned int)BUCKET ? c : (unsigned int)BUCKET;
    }

    // ---- Phase A: 4 row-pairs, 32 unconditional gathers per pair ----
    #pragma unroll
    for (int ip = 0; ip < 4; ip++) {
        const int rA = wave * 8 + ip * 2;
        const int rB = rA + 1;
        const unsigned int* epA =
            (const unsigned int*)(edges16 + (size_t)(m0 + rA) * BUCKET);
        const unsigned int* epB =
            (const unsigned int*)(edges16 + (size_t)(m0 + rB) * BUCKET);

        unsigned int wA[8], wB[8];
        #pragma unroll
        for (int j = 0; j < 8; j++) { wA[j] = epA[j]; wB[j] = epB[j]; }

        unsigned int vA[16], vB[16];
        #pragma unroll
        for (int j = 0; j < 8; j++) {
            vA[2*j]   = nb[(size_t)(wA[j] & 0xffffu) * 64 + lane];
            vA[2*j+1] = nb[(size_t)(wA[j] >> 16)     * 64 + lane];
            vB[2*j]   = nb[(size_t)(wB[j] & 0xffffu) * 64 + lane];
            vB[2*j+1] = nb[(size_t)(wB[j] >> 16)     * 64 + lane];
        }
        unsigned int selfA = nb[(size_t)(m0 + rA) * 64 + lane];
        unsigned int selfB = nb[(size_t)(m0 + rB) * 64 + lane];

        float a0 = 0.f, a1 = 0.f, a2 = 0.f, a3 = 0.f;
        float b0 = 0.f, b1 = 0.f, b2 = 0.f, b3 = 0.f;
        #pragma unroll
        for (int j = 0; j < 16; j += 2) {
            a0 += bf_lo(vA[j]);   a1 += bf_hi(vA[j]);
            a2 += bf_lo(vA[j+1]); a3 += bf_hi(vA[j+1]);
            b0 += bf_lo(vB[j]);   b1 += bf_hi(vB[j]);
            b2 += bf_lo(vB[j+1]); b3 += bf_hi(vB[j+1]);
        }

        // rare overflow (wave-uniform; slots pre-padded -> no selects)
        unsigned int cA = cc[ip * 2], cB = cc[ip * 2 + 1];
        if (cA > 16u) {
            unsigned int cp = (cA + 15u) & ~15u;
            for (unsigned int s = 16; s < cp; s += 16) {
                unsigned int w[8], v[16];
                #pragma unroll
                for (int j = 0; j < 8; j++) w[j] = epA[(s >> 1) + j];
                #pragma unroll
                for (int j = 0; j < 8; j++) {
                    v[2*j]   = nb[(size_t)(w[j] & 0xffffu) * 64 + lane];
                    v[2*j+1] = nb[(size_t)(w[j] >> 16)     * 64 + lane];
                }
                #pragma unroll
                for (int j = 0; j < 16; j += 2) {
                    a0 += bf_lo(v[j]);   a1 += bf_hi(v[j]);
                    a2 += bf_lo(v[j+1]); a3 += bf_hi(v[j+1]);
                }
            }
        }
        if (cB > 16u) {
            unsigned int cp = (cB + 15u) & ~15u;
            for (unsigned int s = 16; s < cp; s += 16) {
                unsigned int w[8], v[16];
                #pragma unroll
                for (int j = 0; j < 8; j++) w[j] = epB[(s >> 1) + j];
                #pragma unroll
                for (int j = 0; j < 8; j++) {
                    v[2*j]   = nb[(size_t)(w[j] & 0xffffu) * 64 + lane];
                    v[2*j+1] = nb[(size_t)(w[j] >> 16)     * 64 + lane];
                }
                #pragma unroll
                for (int j = 0; j < 16; j += 2) {
                    b0 += bf_lo(v[j]);   b1 += bf_hi(v[j]);
                    b2 += bf_lo(v[j+1]); b3 += bf_hi(v[j+1]);
                }
            }
        }

        float invA = 1.0f / fmaxf((float)cA, 1.0f);
        float invB = 1.0f / fmaxf((float)cB, 1.0f);
        h32[rA * (H_STRIDE / 2) + lane]      = pack_bf16x2((a0 + a2) * invA,
                                                           (a1 + a3) * invA);
        h32[rA * (H_STRIDE / 2) + 64 + lane] = selfA;
        h32[rB * (H_STRIDE / 2) + lane]      = pack_bf16x2((b0 + b2) * invB,
                                                           (b1 + b3) * invB);
        h32[rB * (H_STRIDE / 2) + 64 + lane] = selfB;
    }
    __syncthreads();

    // ---- Phase B: MFMA GEMM (R8/R10-verified) ----
    const unsigned short* h = (const unsigned short*)h32;
    const int nbase = wave * 64;
    const int rsel  = lane & 15;   // n (B/D) or m (A) within 16
    const int quad  = lane >> 4;   // k-group / row-group selector

    f32x4 acc[2][4] = {};

    for (int kk = 0; kk < K_DIM; kk += 32) {
        bf16x8 a[2], bw[4];
        #pragma unroll
        for (int mt = 0; mt < 2; mt++) {
            const unsigned short* pa =
                &h[(mt * 16 + rsel) * H_STRIDE + kk + quad * 8];
            a[mt] = *(const bf16x8*)pa;   // ds_read_b128
        }
        int kt = kk >> 5;
        #pragma unroll
        for (int nt = 0; nt < 4; nt++) {
            int n = nbase + nt * 16 + rsel;
            bw[nt] = *(const bf16x8*)&Wp[kt * 8192 + n * 32 + quad * 8];
        }
        #pragma unroll
        for (int mt = 0; mt < 2; mt++)
            #pragma unroll
            for (int nt = 0; nt < 4; nt++)
                acc[mt][nt] = __builtin_amdgcn_mfma_f32_16x16x32_bf16(
                    a[mt], bw[nt], acc[mt][nt], 0, 0, 0);
    }

    // epilogue: bias + relu, f32 store.  C/D: col(n)=lane&15, row(m)=quad*4+reg
    #pragma unroll
    for (int nt = 0; nt < 4; nt++) {
        int n = nbase + nt * 16 + rsel;
        float bn = bias[n];
        #pragma unroll
        for (int mt = 0; mt < 2; mt++) {
            #pragma unroll
            for (int r = 0; r < 4; r++) {
                int m = m0 + mt * 16 + quad * 4 + r;
                if (m < N_NODES) {
                    float v = acc[mt][nt][r] + bn;
                    out[(size_t)m * HIDDEN + n] = fmaxf(v, 0.0f);
                }
            }
        }
    }
}

// ---------------------------------------------------------------------------
extern "C" void kernel_launch(void* const* d_in, const int* in_sizes, int n_in,
                              void* d_out, int out_size, void* d_ws, size_t ws_size,
                              hipStream_t stream) {
    const float* nodes     = (const float*)d_in[0];   // f32 [N,128]
    const int*   senders   = (const int*)d_in[1];     // [E]
    const int*   receivers = (const int*)d_in[2];     // [E]
    const float* W         = (const float*)d_in[3];   // f32 [256,256]
    const float* bias      = (const float*)d_in[4];   // f32 [256]
    float*       out       = (float*)d_out;           // f32 [N,256]

    // workspace layout (~19.7 MB). edges16 first -> 128B-aligned bucket rows.
    unsigned short* edges16 = (unsigned short*)d_ws;                 // [NPAD*BUCKET]
    unsigned int*   cnt     = (unsigned int*)(edges16 + (size_t)NPAD * BUCKET); // [N]
    unsigned int*   nb      = cnt + N_NODES;                         // [(N+1)*64]
    unsigned short* Wp      = (unsigned short*)(nb + (size_t)(N_NODES + 1) * 64); // [65536]

    // pre-fill buckets with pad id ZERO_ROW (0xC350) and zero the counters
    hipMemsetD16Async((hipDeviceptr_t)edges16, 0xC350,
                      (size_t)NPAD * BUCKET, stream);
    hipMemsetAsync(cnt, 0, (size_t)N_NODES * sizeof(unsigned int), stream);

    build_conv_repack<<<dim3(1024), dim3(256), 0, stream>>>(
        senders, receivers, nodes, W, edges16, cnt, nb, Wp);

    gather_mean_gemm<<<dim3(NTILES), dim3(256), 0, stream>>>(
        nb, cnt, edges16, Wp, bias, out);
}